// Round 15
// baseline (1127.830 us; speedup 1.0000x reference)
//
#include <hip/hip_runtime.h>
#include <hip/hip_bf16.h>
#include <cstdint>
#include <cstddef>

#define TK 8192
#define DIM 1024
#define HID 4096
#define NE 8

typedef __attribute__((ext_vector_type(8))) __bf16 bfrag;
typedef __attribute__((ext_vector_type(4))) float ffrag;

static __device__ __forceinline__ ushort f2bf(float f) {
    union { float f; uint32_t u; } v; v.f = f;
    uint32_t r = (v.u + 0x7fffu + ((v.u >> 16) & 1u)) >> 16;   // RNE, finite only
    return (ushort)r;
}

static __device__ __forceinline__ uint4 pack8(float4 a, float4 b) {
    union { ushort u[8]; uint4 q; } pk;
    pk.u[0] = f2bf(a.x); pk.u[1] = f2bf(a.y); pk.u[2] = f2bf(a.z); pk.u[3] = f2bf(a.w);
    pk.u[4] = f2bf(b.x); pk.u[5] = f2bf(b.y); pk.u[6] = f2bf(b.z); pk.u[7] = f2bf(b.w);
    return pk.q;
}

static __device__ __forceinline__ void gld16(const ushort* g, ushort* l) {
    __builtin_amdgcn_global_load_lds(
        (const __attribute__((address_space(1))) unsigned int*)g,
        (__attribute__((address_space(3))) unsigned int*)l, 16, 0, 0);
}

#define BARRIER() asm volatile("s_barrier" ::: "memory")
#define WAITVM(N) asm volatile("s_waitcnt vmcnt(" #N ")" ::: "memory")

// 32-K sub-region [128 rows][32 bf16], superblocks 8 rows x 4 chunks(16B):
// chunk (r,kc) at 16B-slot (r>>3)*32 + kc*8 + (r&7); 0 bank conflicts (r3-r13).
// gld16 sweep: 512 threads x 1 chunk, slot s=tid: r=(s>>5)*8+(s&7), kc=(s>>3)&3.
#define LDSIDX(r, kc) ((((r) >> 3) << 8) + ((kc) << 6) + (((r) & 7) << 3))
#define SLOT_R(s)  ((((s) >> 5) << 3) | ((s) & 7))
#define SLOT_KC(s) (((s) >> 3) & 3)

// ---------------- f32 -> bf16 converts ----------------
__global__ __launch_bounds__(256) void k_cvt(const float* __restrict__ src,
                                             ushort* __restrict__ dst, int n8) {
    int i = blockIdx.x * blockDim.x + threadIdx.x;
    if (i >= n8) return;
    const float4* p = (const float4*)src + (size_t)i * 2;
    ((uint4*)dst)[i] = pack8(p[0], p[1]);
}

// merged x + w1 + w3 convert (1 launch instead of 3)
__global__ __launch_bounds__(256) void k_cvt3(const float* __restrict__ x,
                                              const float* __restrict__ w1,
                                              const float* __restrict__ w3,
                                              ushort* __restrict__ xb,
                                              ushort* __restrict__ wA,
                                              ushort* __restrict__ wB) {
    int i = blockIdx.x * blockDim.x + threadIdx.x;   // 9,437,184 chunks
    const float* src; ushort* dst; int j;
    if (i < (1 << 20))                  { src = x;  dst = xb; j = i; }
    else if (i < (1 << 20) + (1 << 22)) { src = w1; dst = wA; j = i - (1 << 20); }
    else                                { src = w3; dst = wB; j = i - (1 << 20) - (1 << 22); }
    const float4* p = (const float4*)src + (size_t)j * 2;
    ((uint4*)dst)[j] = pack8(p[0], p[1]);
}

// ---------------- router: f64 logits, top-2, renormalized; fused expert count ----------------
__global__ __launch_bounds__(256) void k_router(const float* __restrict__ x,
                                                const float* __restrict__ gw,
                                                int* __restrict__ topi, float* __restrict__ topw,
                                                int* __restrict__ counts) {
    int t = blockIdx.x * 4 + (threadIdx.x >> 6);
    int lane = threadIdx.x & 63;
    if (t >= TK) return;
    double acc[NE];
#pragma unroll
    for (int e = 0; e < NE; ++e) acc[e] = 0.0;
    const float* xr = x + (size_t)t * DIM;
    for (int k = lane; k < DIM; k += 64) {
        double xv = (double)xr[k];
#pragma unroll
        for (int e = 0; e < NE; ++e) acc[e] += xv * (double)gw[e * DIM + k];
    }
#pragma unroll
    for (int e = 0; e < NE; ++e) {
#pragma unroll
        for (int off = 32; off > 0; off >>= 1) acc[e] += __shfl_xor(acc[e], off);
    }
    if (lane == 0) {
        int i1 = 0;
#pragma unroll
        for (int e = 1; e < NE; ++e) if (acc[e] > acc[i1]) i1 = e;
        int i2 = (i1 == 0) ? 1 : 0;
#pragma unroll
        for (int e = 0; e < NE; ++e) if (e != i1 && acc[e] > acc[i2]) i2 = e;
        double w = 1.0 / (1.0 + exp(acc[i2] - acc[i1]));
        topi[t * 2 + 0] = i1; topi[t * 2 + 1] = i2;
        topw[t * 2 + 0] = (float)w; topw[t * 2 + 1] = (float)(1.0 - w);
        atomicAdd(&counts[i1], 1);
        atomicAdd(&counts[i2], 1);
    }
}

// per-expert offsets + M=256 desc list (ffn1) + M=128 desc list (ffn2)
__global__ void k_scan(const int* __restrict__ counts, int* __restrict__ offs,
                       int* __restrict__ cursor,
                       int* __restrict__ desc256, int* __restrict__ nd256,
                       int* __restrict__ desc128, int* __restrict__ nd128) {
    if (threadIdx.x == 0 && blockIdx.x == 0) {
        int s = 0, dA = 0, dB = 0;
        for (int e = 0; e < NE; ++e) {
            offs[e] = s; cursor[e] = s;
            int tA = (counts[e] + 255) >> 8;
            for (int t = 0; t < tA; ++t) desc256[dA++] = (e << 16) | t;
            int tB = (counts[e] + 127) >> 7;
            for (int t = 0; t < tB; ++t) desc128[dB++] = (e << 16) | t;
            s += counts[e];
        }
        offs[NE] = s;
        nd256[0] = dA; nd128[0] = dB;
    }
}

__global__ void k_scatter(const int* __restrict__ topi, const float* __restrict__ topw,
                          int* __restrict__ cursor, int* __restrict__ perm,
                          float* __restrict__ pw) {
    int t = blockIdx.x * blockDim.x + threadIdx.x;
    if (t >= TK) return;
#pragma unroll
    for (int k = 0; k < 2; ++k) {
        int e = topi[t * 2 + k];
        int pos = atomicAdd(&cursor[e], 1);
        perm[pos] = t; pw[pos] = topw[t * 2 + k];
    }
}

// ================= 8-phase GEMM A (m201 schedule, R11/R13-verified, unchanged) =================
__global__ __launch_bounds__(512, 2) void k_ffn1(const ushort* __restrict__ xb,
                                                 const ushort* __restrict__ w1b,
                                                 const ushort* __restrict__ w3b,
                                                 const int* __restrict__ offs,
                                                 const int* __restrict__ perm,
                                                 const int* __restrict__ desc,
                                                 const int* __restrict__ nd_g,
                                                 ushort* __restrict__ H) {
    const int b = blockIdx.x;
    const int d = ((b >> 8) << 3) | (b & 7);
    const int nt = (b >> 3) & 31;
    if (d >= nd_g[0]) return;

    __shared__ ushort lA[2 * 16384];   // 64 KiB
    __shared__ ushort lB[2 * 16384];   // 64 KiB
    __shared__ int lTok[256];

    const int tid = threadIdx.x;
    const int lane = tid & 63, wid = tid >> 6;
    const int l15 = lane & 15, kcc = lane >> 4;
    const int mw = wid >> 2;
    const int wn = (wid & 3) * 64;
    const int mwoff = mw * 8192;
    const int wid512 = wid * 512;

    const int NT1 = DIM / 64;                  // 16 K-tiles

    int aoff[4], boff[4];
#pragma unroll
    for (int i = 0; i < 4; ++i) aoff[i] = LDSIDX(i * 16 + l15, kcc);
#pragma unroll
    for (int j = 0; j < 4; ++j) {
        int brow = wn + j * 16 + l15;
        boff[j] = ((brow >> 7) << 13) + LDSIDX(brow & 127, kcc);
    }

    const int rS = SLOT_R(tid & 511), kcS = SLOT_KC(tid & 511);

    bfrag a[4], br[4][2];
    ffrag acc[8][4];

    const int de = desc[d];
    const int e = de >> 16, mt = de & 0xffff;
    const int m0 = offs[e] + (mt << 8);
    const int nrows = min(256, offs[e + 1] - m0);
    if (tid < 256) lTok[tid] = (tid < nrows) ? perm[m0 + tid] : perm[m0];
    __syncthreads();

    const ushort* pA_[2]; const ushort* pB_[2];
    {
        const size_t ebase = (size_t)e * HID * DIM;
#pragma unroll
        for (int h = 0; h < 2; ++h) {
            pA_[h] = xb + (size_t)lTok[h * 128 + rS] * DIM + kcS * 8;
            int brow = h * 128 + rS;
            int gg = brow >> 4;
            int hc = nt * 128 + (((gg >> 1) << 4) | (brow & 15));
            pB_[h] = ((gg & 1) ? w3b : w1b) + ebase + (size_t)hc * DIM + kcS * 8;
        }
    }

#pragma unroll
    for (int i = 0; i < 8; ++i)
#pragma unroll
        for (int j = 0; j < 4; ++j) acc[i][j] = (ffrag)0.f;

#define SGA1(DB, HH, TT) do { if ((TT) < NT1) { \
        gld16(pA_[HH] + (TT) * 64,      lA + (DB) * 16384 + (HH) * 8192 + wid512); \
        gld16(pA_[HH] + (TT) * 64 + 32, lA + (DB) * 16384 + (HH) * 8192 + 4096 + wid512); } } while (0)
#define SGB1(DB, HH, TT) do { if ((TT) < NT1) { \
        gld16(pB_[HH] + (TT) * 64,      lB + (DB) * 16384 + (HH) * 8192 + wid512); \
        gld16(pB_[HH] + (TT) * 64 + 32, lB + (DB) * 16384 + (HH) * 8192 + 4096 + wid512); } } while (0)
#define RDB1(DB) do { _Pragma("unroll") for (int j = 0; j < 4; ++j) { \
        br[j][0] = *(const bfrag*)&lB[(DB) * 16384 + boff[j]]; \
        br[j][1] = *(const bfrag*)&lB[(DB) * 16384 + boff[j] + 4096]; } } while (0)
#define RDA1(DB, Q, S) do { _Pragma("unroll") for (int i = 0; i < 4; ++i) \
        a[i] = *(const bfrag*)&lA[(DB) * 16384 + mwoff + (S) * 4096 + (Q) * 2048 + aoff[i]]; } while (0)
#define MM1(Q, S) do { __builtin_amdgcn_s_setprio(1); \
        _Pragma("unroll") for (int i = 0; i < 4; ++i) \
        _Pragma("unroll") for (int j = 0; j < 4; ++j) \
            acc[(Q) * 4 + i][j] = __builtin_amdgcn_mfma_f32_16x16x32_bf16(a[i], br[j][S], acc[(Q) * 4 + i][j], 0, 0, 0); \
        __builtin_amdgcn_s_setprio(0); } while (0)
#define PH1(DB, Q, S, BL, STG, WT) do { \
        if (BL) RDB1(DB); RDA1(DB, Q, S); STG; WT; BARRIER(); MM1(Q, S); BARRIER(); } while (0)

    // prologue: T0 full (db0) + T1.B (db1); vmcnt(4) leaves T1.B in flight
    SGA1(0, 0, 0); SGA1(0, 1, 0); SGB1(0, 0, 0); SGB1(0, 1, 0);
    SGB1(1, 0, 1); SGB1(1, 1, 1);
    WAITVM(4);
    BARRIER();

#pragma unroll 1
    for (int it = 0; it < NT1 / 2; ++it) {
        const int t1 = 2 * it + 1, t2 = 2 * it + 2, t3 = 2 * it + 3;
        const bool last = (it == NT1 / 2 - 1);
        PH1(0, 0, 0, 1, SGA1(1, 0, t1), );
        PH1(0, 1, 0, 0, SGA1(1, 1, t1), );
        PH1(0, 0, 1, 0, SGB1(0, 0, t2), );
        PH1(0, 1, 1, 0, SGB1(0, 1, t2), if (last) { WAITVM(0); } else { WAITVM(4); });
        PH1(1, 0, 0, 1, SGA1(0, 0, t2), );
        PH1(1, 1, 0, 0, SGA1(0, 1, t2), );
        PH1(1, 0, 1, 0, SGB1(1, 0, t3), );
        PH1(1, 1, 1, 0, SGB1(1, 1, t3), if (last) { WAITVM(0); } else { WAITVM(4); });
    }
#undef PH1
#undef MM1
#undef RDA1
#undef RDB1
#undef SGB1
#undef SGA1

    // epilogue: frag pairs (jf, jf+1) = (h1, h3) for same 16 hidden cols
#pragma unroll
    for (int i = 0; i < 8; ++i) {
        int rbase = mw * 128 + i * 16 + ((lane >> 4) << 2);
#pragma unroll
        for (int q = 0; q < 4; ++q) {
            int rl = rbase + q;
            if (rl >= nrows) continue;
            size_t rowoff = (size_t)(m0 + rl) * HID;
#pragma unroll
            for (int jf = 0; jf < 4; jf += 2) {
                int gg = (wn >> 4) + jf;
                int col = nt * 128 + ((gg >> 1) << 4) + l15;
                float h1 = acc[i][jf][q], h3 = acc[i][jf + 1][q];
                H[rowoff + col] = f2bf((h1 / (1.f + __expf(-h1))) * h3);
            }
        }
    }
}

// ================= GEMM B: tri-buffered 2-phase/tile (stage slack >= 2 phases) =================
// 128 H-rows x 256 out-cols, BK=64, 8 waves (2M x 4N), per-wave 64x64.
// LDS 145 KiB: 3 x (A 16K + B 32K). Sweep = 1 gld16/thread (8 KiB); 6 sweeps/tile.
// Tile t uses buf t%3; during tile t stage tile t+2 into buf (t+2)%3 (3 sweeps
// per phase). Ledger: prev wait left tile-(t+1)'s 6 in flight; at P2(t) outstanding
// = 6(t+1) + 6(t+2) -> WAITVM(6) retires t+1's batch (issued 2-4 phases ago) before
// P1(t+1) ds_reads. Tail: t+2 >= NT -> WAITVM(0) (only stale loads remain).
// Epilogue: pw-weighted f32 atomicAdd into out (2 commutative adds/elem = deterministic).
__global__ __launch_bounds__(512, 1) void k_ffn2(const ushort* __restrict__ Hs,
                                                 const ushort* __restrict__ w2b,
                                                 const int* __restrict__ offs,
                                                 const int* __restrict__ perm,
                                                 const float* __restrict__ pw,
                                                 const int* __restrict__ desc,
                                                 const int* __restrict__ nd_g,
                                                 float* __restrict__ out) {
    const int b = blockIdx.x;
    const int d = b >> 2, nt = b & 3;
    if (d >= nd_g[0]) return;

    __shared__ ushort lA[3 * 8192];    // 48 KiB
    __shared__ ushort lB[3 * 16384];   // 96 KiB
    __shared__ int lTok[128];
    __shared__ float lPw[128];

    const int tid = threadIdx.x;
    const int lane = tid & 63, wid = tid >> 6;
    const int l15 = lane & 15, kcc = lane >> 4;
    const int mw = wid >> 2;
    const int wn = (wid & 3) * 64;
    const int wid512 = wid * 512;

    const int NT2 = HID / 64;                  // 64 K-tiles

    int aoff[4], boff[4];
#pragma unroll
    for (int i = 0; i < 4; ++i) aoff[i] = LDSIDX(mw * 64 + i * 16 + l15, kcc);
#pragma unroll
    for (int j = 0; j < 4; ++j) {
        int brow = wn + j * 16 + l15;
        boff[j] = ((brow >> 7) << 13) + LDSIDX(brow & 127, kcc);
    }

    const int rS = SLOT_R(tid & 511), kcS = SLOT_KC(tid & 511);

    bfrag a[4], br[4][2];
    ffrag acc[4][4];

    const int de = desc[d];
    const int e = de >> 16, mt = de & 0xffff;
    const int m0 = offs[e] + (mt << 7);
    const int nrows = min(128, offs[e + 1] - m0);
    if (tid < 128) {
        bool v = tid < nrows;
        lTok[tid] = v ? perm[m0 + tid] : 0;
        lPw[tid]  = v ? pw[m0 + tid] : 0.f;
    }
    __syncthreads();

    int posA = m0 + rS; if (posA > 2 * TK - 1) posA = 2 * TK - 1;   // clamp into H
    const ushort* pA_ = Hs + (size_t)posA * HID + kcS * 8;
    const ushort* pB_[2];
    {
        const size_t ebase = (size_t)e * DIM * HID;
#pragma unroll
        for (int h = 0; h < 2; ++h)
            pB_[h] = w2b + ebase + (size_t)(nt * 256 + h * 128 + rS) * HID + kcS * 8;
    }

#pragma unroll
    for (int i = 0; i < 4; ++i)
#pragma unroll
        for (int j = 0; j < 4; ++j) acc[i][j] = (ffrag)0.f;

#define SGA2(BUF, S, TT) do { if ((TT) < NT2) \
        gld16(pA_ + (TT) * 64 + (S) * 32, lA + (BUF) * 8192 + (S) * 4096 + wid512); } while (0)
#define SGB2(BUF, HH, S, TT) do { if ((TT) < NT2) \
        gld16(pB_[HH] + (TT) * 64 + (S) * 32, lB + (BUF) * 16384 + (HH) * 8192 + (S) * 4096 + wid512); } while (0)
#define RDB2(BUF) do { _Pragma("unroll") for (int j = 0; j < 4; ++j) { \
        br[j][0] = *(const bfrag*)&lB[(BUF) * 16384 + boff[j]]; \
        br[j][1] = *(const bfrag*)&lB[(BUF) * 16384 + boff[j] + 4096]; } } while (0)
#define RDA2(BUF, S) do { _Pragma("unroll") for (int i = 0; i < 4; ++i) \
        a[i] = *(const bfrag*)&lA[(BUF) * 8192 + (S) * 4096 + aoff[i]]; } while (0)
#define MM2(S) do { __builtin_amdgcn_s_setprio(1); \
        _Pragma("unroll") for (int i = 0; i < 4; ++i) \
        _Pragma("unroll") for (int j = 0; j < 4; ++j) \
            acc[i][j] = __builtin_amdgcn_mfma_f32_16x16x32_bf16(a[i], br[j][S], acc[i][j], 0, 0, 0); \
        __builtin_amdgcn_s_setprio(0); } while (0)

    // prologue: tile0 -> buf0 (6 sweeps), tile1 -> buf1 (6); retire tile0, keep tile1 in flight
    SGA2(0, 0, 0); SGA2(0, 1, 0);
    SGB2(0, 0, 0, 0); SGB2(0, 0, 1, 0); SGB2(0, 1, 0, 0); SGB2(0, 1, 1, 0);
    SGA2(1, 0, 1); SGA2(1, 1, 1);
    SGB2(1, 0, 0, 1); SGB2(1, 0, 1, 1); SGB2(1, 1, 0, 1); SGB2(1, 1, 1, 1);
    WAITVM(6);
    BARRIER();

    int cur = 0, nx2 = 2;
#pragma unroll 1
    for (int t = 0; t < NT2; ++t) {
        const int tt = t + 2;
        // P1: read cur (8 B-frags + 4 A-frags), stage 3 sweeps of tile t+2
        RDB2(cur); RDA2(cur, 0);
        SGA2(nx2, 0, tt); SGA2(nx2, 1, tt); SGB2(nx2, 0, 0, tt);
        BARRIER(); MM2(0); BARRIER();
        // P2: read cur A-S1, stage 3 sweeps, counted wait (retires tile t+1's batch)
        RDA2(cur, 1);
        SGB2(nx2, 0, 1, tt); SGB2(nx2, 1, 0, tt); SGB2(nx2, 1, 1, tt);
        if (tt < NT2) { WAITVM(6); } else { WAITVM(0); }
        BARRIER(); MM2(1); BARRIER();
        cur = (cur == 2) ? 0 : cur + 1;
        nx2 = (nx2 == 2) ? 0 : nx2 + 1;
    }
#undef MM2
#undef RDA2
#undef RDB2
#undef SGB2
#undef SGA2

    // epilogue: out[tok] += pw * acc (exactly 2 adds/elem, commutative => deterministic)
#pragma unroll
    for (int i = 0; i < 4; ++i) {
        int rbase = mw * 64 + i * 16 + ((lane >> 4) << 2);
#pragma unroll
        for (int q = 0; q < 4; ++q) {
            int rl = rbase + q;
            if (rl >= nrows) continue;
            int tok = lTok[rl];
            float wgt = lPw[rl];
            size_t rowoff = (size_t)tok * DIM;
#pragma unroll
            for (int j = 0; j < 4; ++j) {
                int col = nt * 256 + wn + j * 16 + l15;
                atomicAdd(&out[rowoff + col], acc[i][j][q] * wgt);
            }
        }
    }
}

extern "C" void kernel_launch(void* const* d_in, const int* in_sizes, int n_in,
                              void* d_out, int out_size, void* d_ws, size_t ws_size,
                              hipStream_t stream) {
    const float* x  = (const float*)d_in[0];
    const float* gw = (const float*)d_in[1];
    const float* w1 = (const float*)d_in[2];
    const float* w2 = (const float*)d_in[3];   // dict order: x, gate_w, w1, w2, w3 !
    const float* w3 = (const float*)d_in[4];
    float* out = (float*)d_out;

    char* ws = (char*)d_ws;
    int*    topi    = (int*)(ws + 0);              // 64 KB
    float*  topw    = (float*)(ws + 65536);        // 64 KB
    int*    perm    = (int*)(ws + 131072);         // 64 KB
    float*  pw      = (float*)(ws + 196608);       // 64 KB
    int*    counts  = (int*)(ws + 262144);
    int*    offs    = (int*)(ws + 262144 + 256);
    int*    cursor  = (int*)(ws + 262144 + 512);
    int*    nd256   = (int*)(ws + 262144 + 768);
    int*    nd128   = (int*)(ws + 262144 + 772);
    int*    desc256 = (int*)(ws + 262144 + 1024);  // <= ~80 entries
    int*    desc128 = (int*)(ws + 262144 + 2048);  // <= ~140 entries

    const size_t OFF_XB = 655360;                       // xb: 16 MiB
    const size_t OFF_H  = OFF_XB + 16777216;            // H : 128 MiB (bf16 16384x4096)
    const size_t OFF_WA = OFF_H + 134217728;            // w1b, later w2b: 64 MiB
    const size_t OFF_WB = OFF_WA + 67108864;            // w3b: 64 MiB

    ushort* xb  = (ushort*)(ws + OFF_XB);
    ushort* H   = (ushort*)(ws + OFF_H);
    ushort* wA  = (ushort*)(ws + OFF_WA);
    ushort* wB  = (ushort*)(ws + OFF_WB);

    hipMemsetAsync(counts, 0, 32, stream);
    hipMemsetAsync(out, 0, (size_t)out_size * sizeof(float), stream);

    k_router<<<dim3(TK / 4), 256, 0, stream>>>(x, gw, topi, topw, counts);
    k_scan<<<dim3(1), 64, 0, stream>>>(counts, offs, cursor, desc256, nd256, desc128, nd128);
    k_scatter<<<dim3(TK / 256), 256, 0, stream>>>(topi, topw, cursor, perm, pw);

    // x + w1 + w3 converts in one launch: 9,437,184 chunks
    k_cvt3<<<dim3(36864), 256, 0, stream>>>(x, w1, w3, xb, wA, wB);

    // grid: q<=8 (worst-case 71 descs) x 32 nt x 8 xcd
    k_ffn1<<<dim3(9 * 256), 512, 0, stream>>>(xb, wA, wB, offs, perm, desc256, nd256, H);

    // w1b dead now; reuse its slot for w2b
    k_cvt<<<dim3((NE * DIM * HID / 8) / 256), 256, 0, stream>>>(w2, wA, NE * DIM * HID / 8);

    // 136 descs max x 4 nt panels
    k_ffn2<<<dim3(136 * 4), 512, 0, stream>>>(H, wA, offs, perm, pw, desc128, nd128, out);
}